// Round 3
// baseline (3144.470 us; speedup 1.0000x reference)
//
#include <hip/hip_runtime.h>
#include <hip/hip_bf16.h>

typedef __attribute__((ext_vector_type(8))) short s16x8;
typedef __attribute__((ext_vector_type(4))) float f32x4;

__device__ __forceinline__ ushort f2bf(float x) {
  __hip_bfloat16 b = __float2bfloat16(x);
  return *reinterpret_cast<ushort*>(&b);
}

__device__ __forceinline__ float sigm_fast(float z) {
  return __builtin_amdgcn_rcpf(1.0f + __builtin_amdgcn_exp2f(z * -1.44269504088896f));
}

// ---------------------------------------------------------------------------
// K0: pack weights (unchanged).
// ---------------------------------------------------------------------------
__global__ __launch_bounds__(256) void pack_weights(
    const float* __restrict__ Wf, const float* __restrict__ Wi,
    const float* __restrict__ Wg, const float* __restrict__ Wo,
    const float* __restrict__ Rf, const float* __restrict__ Ri,
    const float* __restrict__ Rg, const float* __restrict__ Ro,
    const float* __restrict__ bfp, const float* __restrict__ bip,
    const float* __restrict__ bgp, const float* __restrict__ bop,
    ushort* __restrict__ Wx, ushort* __restrict__ Rs, float* __restrict__ bp)
{
  const int p = blockIdx.x * 8 + (threadIdx.x >> 5);
  const int kk = (threadIdx.x & 31) * 16;
  const int gate = p & 3;
  const int hcol = (p >> 5) * 8 + ((p >> 4) & 1) * 4 + ((p & 15) >> 2);
  const float* W = (gate == 0) ? Wf : (gate == 1) ? Wi : (gate == 2) ? Wg : Wo;
  const float* R = (gate == 0) ? Rf : (gate == 1) ? Ri : (gate == 2) ? Rg : Ro;
  union { ushort u[16]; s16x8 v[2]; } wb, rb;
#pragma unroll
  for (int e = 0; e < 16; ++e) {
    const int k = kk + e;
    wb.u[e] = f2bf(W[(size_t)k * 512 + hcol]);
    rb.u[e] = f2bf(W[(size_t)(512 + k) * 512 + hcol] + R[(size_t)k * 512 + hcol]);
  }
  *(s16x8*)(Wx + (size_t)p * 512 + kk)     = wb.v[0];
  *(s16x8*)(Wx + (size_t)p * 512 + kk + 8) = wb.v[1];
  *(s16x8*)(Rs + (size_t)p * 512 + kk)     = rb.v[0];
  *(s16x8*)(Rs + (size_t)p * 512 + kk + 8) = rb.v[1];
  if ((threadIdx.x & 31) == 0) {
    const float* B = (gate == 0) ? bfp : (gate == 1) ? bip : (gate == 2) ? bgp : bop;
    bp[p] = B[hcol];
  }
}

// ---------------------------------------------------------------------------
// K1: pre-swizzle x into A-fragment layout (unchanged).
// ---------------------------------------------------------------------------
__global__ __launch_bounds__(256) void swizzle_x(
    const float* __restrict__ x, ushort* __restrict__ xsw)
{
  __shared__ ushort xl[64 * 520];
  const int t = blockIdx.x;
  const int tid = threadIdx.x;
  const float4* x4 = (const float4*)(x + (size_t)t * 32768);
#pragma unroll 4
  for (int j = 0; j < 32; ++j) {
    const int i4 = j * 256 + tid;
    const float4 v = x4[i4];
    const int base = i4 * 4;
    const int row = base >> 9;
    const int col = base & 511;
    ushort4 u;
    u.x = f2bf(v.x); u.y = f2bf(v.y); u.z = f2bf(v.z); u.w = f2bf(v.w);
    *(ushort4*)(&xl[row * 520 + col]) = u;
  }
  __syncthreads();
#pragma unroll 4
  for (int j = 0; j < 16; ++j) {
    const int F = j * 256 + tid;
    const int l = F & 63;
    const int kc = (F >> 6) & 15;
    const int mt = F >> 10;
    const int row = mt * 16 + (l & 15);
    const int k0 = kc * 32 + (l >> 4) * 8;
    const s16x8 v = *(const s16x8*)(&xl[row * 520 + k0]);
    *(s16x8*)(&xsw[((size_t)t * 4096 + F) * 8]) = v;
  }
}

// ---------------------------------------------------------------------------
// K2: Zx chunk GEMM (unchanged).
// ---------------------------------------------------------------------------
__global__ __launch_bounds__(512, 1) void zx_gemm(
    const ushort* __restrict__ xsw, const ushort* __restrict__ Wx,
    float* __restrict__ zx, int t0, int tcnt)
{
  __shared__ ushort lbuf[32768];
  const int pg = blockIdx.x;
  const int tgrp = blockIdx.y;
  const int tid = threadIdx.x;
  const int wid = tid >> 6;
  const int lane = tid & 63;
  const int mpair = wid >> 2;
  const int np = wid & 3;
  const int q = pg * 4 + np;
  const int l15 = lane & 15;
  const int hi = lane >> 4;

  s16x8 Bg[2][16];
#pragma unroll
  for (int nt = 0; nt < 2; ++nt)
#pragma unroll
    for (int kc = 0; kc < 16; ++kc)
      Bg[nt][kc] = *(const s16x8*)(Wx + (size_t)(q * 32 + nt * 16 + l15) * 512 + kc * 32 + hi * 8);

  for (int tt = 0; tt < tcnt; ++tt) {
    const int tl = tgrp * tcnt + tt;
    const int t = t0 + tl;
#pragma unroll
    for (int j = 0; j < 8; ++j) {
      const int fid = j * 512 + tid;
      *(s16x8*)(&lbuf[(size_t)fid * 8]) =
          *(const s16x8*)(xsw + ((size_t)t * 4096 + fid) * 8);
    }
    __syncthreads();
#pragma unroll
    for (int a = 0; a < 2; ++a) {
      const int mt = mpair * 2 + a;
      f32x4 acc0 = {0.f, 0.f, 0.f, 0.f};
      f32x4 acc1 = {0.f, 0.f, 0.f, 0.f};
#pragma unroll
      for (int kc = 0; kc < 16; ++kc) {
        const s16x8 af = *(const s16x8*)(&lbuf[((size_t)(mt * 16 + kc) * 64 + lane) * 8]);
        acc0 = __builtin_amdgcn_mfma_f32_16x16x32_bf16(af, Bg[0][kc], acc0, 0, 0, 0);
        acc1 = __builtin_amdgcn_mfma_f32_16x16x32_bf16(af, Bg[1][kc], acc1, 0, 0, 0);
      }
      float* o = zx + ((((size_t)tl * 4 + mt) * 64 + q) * 64 + lane) * 8;
      *(f32x4*)(o)     = acc0;
      *(f32x4*)(o + 4) = acc1;
    }
    __syncthreads();
  }
}

// ---------------------------------------------------------------------------
// K3: recurrence. 16 WGs = 2 teams x 8 members; each WG interleaves TWO
// independent batch-group chains (A = team*2, B = team*2+1) sharing the same
// register-pinned Rsum fragments. Publish = LDS transpose -> 16B agent-scope
// stores; flag after vmcnt(0); dout plain stores AFTER the flag.
// ---------------------------------------------------------------------------
__global__ __launch_bounds__(512, 1) void rec_kernel(
    const ushort* __restrict__ Rs, const float* __restrict__ bp,
    const float* __restrict__ zx, ushort* __restrict__ hbuf,
    float* __restrict__ csave, int* __restrict__ cnt,
    float* __restrict__ dout, int t0, int CH)
{
  __shared__ ushort hslA[8192];   // 16KB swizzled h tile, chain A
  __shared__ ushort hslB[8192];   // 16KB, chain B
  __shared__ ushort tbuf[1024];   // 2KB publish-transpose (per-wave 128 ushorts)

  const int bid = blockIdx.x;     // 0..15
  const int team = bid >> 3;      // 0,1
  const int tid = threadIdx.x;
  const int wid = tid >> 6;
  const int lane = tid & 63;
  const int q = (bid & 7) * 8 + wid;   // packed col-group 0..63
  const int gA = team * 2;
  const int gB = team * 2 + 1;
  const int gate = lane & 3;
  const int l15 = lane & 15;
  const int hi = lane >> 4;

  // ---- Rsum fragments: load once, pin in VGPRs (opaque asm) ----
  f32x4 Brg[2][16];
#pragma unroll
  for (int nt = 0; nt < 2; ++nt)
#pragma unroll
    for (int kc = 0; kc < 16; ++kc) {
      Brg[nt][kc] = *(const f32x4*)(Rs + (size_t)(q * 32 + nt * 16 + l15) * 512 + kc * 32 + hi * 8);
      asm volatile("" : "+v"(Brg[nt][kc]));
    }

  const float b0 = bp[q * 32 + l15];
  const float b1 = bp[q * 32 + 16 + l15];

  float cA[2][4], cB[2][4];
  float* cspA = csave + ((size_t)((bid * 8 + wid) * 64 + lane) * 2 + 0) * 8;
  float* cspB = cspA + 8;
  if (t0 == 0) {
#pragma unroll
    for (int i = 0; i < 2; ++i)
#pragma unroll
      for (int r = 0; r < 4; ++r) { cA[i][r] = 0.0f; cB[i][r] = 0.0f; }
  } else {
#pragma unroll
    for (int i = 0; i < 2; ++i)
#pragma unroll
      for (int r = 0; r < 4; ++r) { cA[i][r] = cspA[i * 4 + r]; cB[i][r] = cspB[i * 4 + r]; }
  }

  const int srow = hi * 4 + gate;          // local output row 0..15
  const int hcol0 = q * 8 + (l15 >> 2);

  // staging address precompute
  const int crow = tid >> 5;               // 0..15
  const int cbyte = (tid & 31) * 32;
  const int cswz = (crow & 7) << 4;
  const int srcofs = crow * 512 + (cbyte >> 1);
  const int wofs0 = (crow * 1024 + (cbyte ^ cswz)) >> 1;
  const int wofs1 = (crow * 1024 + ((cbyte + 16) ^ cswz)) >> 1;
  const int abase = l15 * 1024 + hi * 16;
  const int aswz = (l15 & 7) << 4;

  int* const cptrA = cnt + gA * 16;
  int* const cptrB = cnt + gB * 16;

  // zx preload for step 0
  const float* zpA = zx + (((size_t)0 * 4 + gA) * 64 + q) * 64 * 8 + (size_t)lane * 8;
  const float* zpB = zx + (((size_t)0 * 4 + gB) * 64 + q) * 64 * 8 + (size_t)lane * 8;
  float4 zA0 = *(const float4*)zpA, zA1 = *(const float4*)(zpA + 4);
  float4 zB0 = *(const float4*)zpB, zB1 = *(const float4*)(zpB + 4);

#define GATES(ACC0, ACC1, Z0, Z1, CST, HV0, HV1, CV0, CV1)                      \
  {                                                                              \
    float h_[2][4];                                                              \
    _Pragma("unroll")                                                            \
    for (int nt = 0; nt < 2; ++nt) {                                             \
      _Pragma("unroll")                                                          \
      for (int r = 0; r < 4; ++r) {                                              \
        float z = (nt ? (ACC1)[r] : (ACC0)[r]);                                  \
        z += nt ? ((r==0)?(Z1).x:(r==1)?(Z1).y:(r==2)?(Z1).z:(Z1).w)             \
                : ((r==0)?(Z0).x:(r==1)?(Z0).y:(r==2)?(Z0).z:(Z0).w);            \
        z += nt ? b1 : b0;                                                       \
        const float zz = (gate == 2) ? z + z : z;                                \
        const float s = sigm_fast(zz);                                           \
        const float act = (gate == 2) ? (s + s - 1.0f) : s;                      \
        const int ai = __float_as_int(act);                                      \
        const float fv = __int_as_float(__builtin_amdgcn_mov_dpp(ai, 0x00, 0xF, 0xF, true)); \
        const float iv = __int_as_float(__builtin_amdgcn_mov_dpp(ai, 0x55, 0xF, 0xF, true)); \
        const float gv = __int_as_float(__builtin_amdgcn_mov_dpp(ai, 0xAA, 0xF, 0xF, true)); \
        const float ov = __int_as_float(__builtin_amdgcn_mov_dpp(ai, 0xFF, 0xF, 0xF, true)); \
        const float cn = fmaf(fv, CST[nt][r], iv * gv);                          \
        CST[nt][r] = cn;                                                         \
        const float s2 = sigm_fast(cn + cn);                                     \
        h_[nt][r] = ov * (s2 + s2 - 1.0f);                                       \
      }                                                                          \
    }                                                                            \
    HV0 = (gate==0)?h_[0][0]:(gate==1)?h_[0][1]:(gate==2)?h_[0][2]:h_[0][3];     \
    HV1 = (gate==0)?h_[1][0]:(gate==1)?h_[1][1]:(gate==2)?h_[1][2]:h_[1][3];     \
    CV0 = (gate==0)?CST[0][0]:(gate==1)?CST[0][1]:(gate==2)?CST[0][2]:CST[0][3]; \
    CV1 = (gate==0)?CST[1][0]:(gate==1)?CST[1][1]:(gate==2)?CST[1][2]:CST[1][3]; \
  }

#define PUBLISH(HV0, HV1, SLOT, CPTR)                                            \
  {                                                                              \
    tbuf[wid * 128 + srow * 8 + (l15 >> 2)]     = f2bf(HV0);                     \
    tbuf[wid * 128 + srow * 8 + (l15 >> 2) + 4] = f2bf(HV1);                     \
    asm volatile("s_waitcnt lgkmcnt(0)" ::: "memory");                           \
    __builtin_amdgcn_sched_barrier(0);                                           \
    if (lane < 16) {                                                             \
      const unsigned long long* rp = (const unsigned long long*)&tbuf[wid * 128 + lane * 8]; \
      ushort* dst = (SLOT) + lane * 512 + q * 8;                                 \
      __hip_atomic_store((unsigned long long*)dst, rp[0],                        \
                         __ATOMIC_RELAXED, __HIP_MEMORY_SCOPE_AGENT);            \
      __hip_atomic_store((unsigned long long*)(dst + 4), rp[1],                  \
                         __ATOMIC_RELAXED, __HIP_MEMORY_SCOPE_AGENT);            \
    }                                                                            \
    asm volatile("s_waitcnt vmcnt(0)" ::: "memory");                             \
    __syncthreads();                                                             \
    if (tid == 0)                                                                \
      __hip_atomic_fetch_add((CPTR), 1, __ATOMIC_RELAXED, __HIP_MEMORY_SCOPE_AGENT); \
  }

  for (int tl = 0; tl < CH; ++tl) {
    const int t = t0 + tl;

    // ---- phase 0: spins + h loads for both chains ----
    if (tl > 0) {
      const int tgt = 8 * t;
      while (__hip_atomic_load(cptrA, __ATOMIC_RELAXED, __HIP_MEMORY_SCOPE_AGENT) < tgt) {}
      asm volatile("" ::: "memory");
    }
    const ushort* hsA = hbuf + ((size_t)tl * 4 + gA) * 8192;
    const s16x8 la0 = *(const s16x8*)(hsA + srcofs);
    const s16x8 la1 = *(const s16x8*)(hsA + srcofs + 8);
    if (tl > 0) {
      const int tgt = 8 * t;
      while (__hip_atomic_load(cptrB, __ATOMIC_RELAXED, __HIP_MEMORY_SCOPE_AGENT) < tgt) {}
      asm volatile("" ::: "memory");
    }
    const ushort* hsB = hbuf + ((size_t)tl * 4 + gB) * 8192;
    const s16x8 lb0 = *(const s16x8*)(hsB + srcofs);
    const s16x8 lb1 = *(const s16x8*)(hsB + srcofs + 8);

    // ================= chain A =================
    *(s16x8*)(&hslA[wofs0]) = la0;
    *(s16x8*)(&hslA[wofs1]) = la1;
    __syncthreads();
    f32x4 ac0 = {0.f, 0.f, 0.f, 0.f};
    f32x4 ac1 = {0.f, 0.f, 0.f, 0.f};
#pragma unroll
    for (int kc = 0; kc < 16; ++kc) {
      const s16x8 a = *(const s16x8*)(&hslA[((abase + kc * 64) ^ aswz) >> 1]);
      ac0 = __builtin_amdgcn_mfma_f32_16x16x32_bf16(a, __builtin_bit_cast(s16x8, Brg[0][kc]), ac0, 0, 0, 0);
      ac1 = __builtin_amdgcn_mfma_f32_16x16x32_bf16(a, __builtin_bit_cast(s16x8, Brg[1][kc]), ac1, 0, 0, 0);
    }
    float hvA0, hvA1, cvA0, cvA1;
    GATES(ac0, ac1, zA0, zA1, cA, hvA0, hvA1, cvA0, cvA1);
    {
      ushort* hn = hbuf + ((size_t)(tl + 1) * 4 + gA) * 8192;
      PUBLISH(hvA0, hvA1, hn, cptrA);
    }
    // post-flag: dout + handoff + zx prefetch (off the sync path)
    {
      const size_t drow = (size_t)(gA * 16 + srow) * 512;
      dout[(size_t)t * 32768 + drow + hcol0]     = hvA0;
      dout[(size_t)t * 32768 + drow + hcol0 + 4] = hvA1;
      if (t == 511) {
        dout[(size_t)16777216 + drow + hcol0]     = hvA0;
        dout[(size_t)16777216 + drow + hcol0 + 4] = hvA1;
        dout[(size_t)16809984 + drow + hcol0]     = cvA0;
        dout[(size_t)16809984 + drow + hcol0 + 4] = cvA1;
      }
      if (tl == CH - 1) {
        ushort* h0 = hbuf + (size_t)gA * 8192;
        h0[srow * 512 + hcol0]     = f2bf(hvA0);
        h0[srow * 512 + hcol0 + 4] = f2bf(hvA1);
      } else {
        const float* zn = zx + ((((size_t)(tl + 1) * 4 + gA) * 64 + q) * 64 + lane) * 8;
        zA0 = *(const float4*)zn;
        zA1 = *(const float4*)(zn + 4);
      }
    }

    // ================= chain B =================
    *(s16x8*)(&hslB[wofs0]) = lb0;
    *(s16x8*)(&hslB[wofs1]) = lb1;
    __syncthreads();
    f32x4 bc0 = {0.f, 0.f, 0.f, 0.f};
    f32x4 bc1 = {0.f, 0.f, 0.f, 0.f};
#pragma unroll
    for (int kc = 0; kc < 16; ++kc) {
      const s16x8 a = *(const s16x8*)(&hslB[((abase + kc * 64) ^ aswz) >> 1]);
      bc0 = __builtin_amdgcn_mfma_f32_16x16x32_bf16(a, __builtin_bit_cast(s16x8, Brg[0][kc]), bc0, 0, 0, 0);
      bc1 = __builtin_amdgcn_mfma_f32_16x16x32_bf16(a, __builtin_bit_cast(s16x8, Brg[1][kc]), bc1, 0, 0, 0);
    }
    float hvB0, hvB1, cvB0, cvB1;
    GATES(bc0, bc1, zB0, zB1, cB, hvB0, hvB1, cvB0, cvB1);
    {
      ushort* hn = hbuf + ((size_t)(tl + 1) * 4 + gB) * 8192;
      PUBLISH(hvB0, hvB1, hn, cptrB);
    }
    {
      const size_t drow = (size_t)(gB * 16 + srow) * 512;
      dout[(size_t)t * 32768 + drow + hcol0]     = hvB0;
      dout[(size_t)t * 32768 + drow + hcol0 + 4] = hvB1;
      if (t == 511) {
        dout[(size_t)16777216 + drow + hcol0]     = hvB0;
        dout[(size_t)16777216 + drow + hcol0 + 4] = hvB1;
        dout[(size_t)16809984 + drow + hcol0]     = cvB0;
        dout[(size_t)16809984 + drow + hcol0 + 4] = cvB1;
      }
      if (tl == CH - 1) {
        ushort* h0 = hbuf + (size_t)gB * 8192;
        h0[srow * 512 + hcol0]     = f2bf(hvB0);
        h0[srow * 512 + hcol0 + 4] = f2bf(hvB1);
      } else {
        const float* zn = zx + ((((size_t)(tl + 1) * 4 + gB) * 64 + q) * 64 + lane) * 8;
        zB0 = *(const float4*)zn;
        zB1 = *(const float4*)(zn + 4);
      }
    }
  }

#pragma unroll
  for (int i = 0; i < 2; ++i)
#pragma unroll
    for (int r = 0; r < 4; ++r) { cspA[i * 4 + r] = cA[i][r]; cspB[i * 4 + r] = cB[i][r]; }
#undef GATES
#undef PUBLISH
}

// ---------------------------------------------------------------------------
extern "C" void kernel_launch(void* const* d_in, const int* in_sizes, int n_in,
                              void* d_out, int out_size, void* d_ws, size_t ws_size,
                              hipStream_t stream)
{
  const float* x   = (const float*)d_in[0];
  const float* Wf  = (const float*)d_in[1];
  const float* bfp = (const float*)d_in[2];
  const float* Wi  = (const float*)d_in[3];
  const float* bip = (const float*)d_in[4];
  const float* Wg  = (const float*)d_in[5];
  const float* bgp = (const float*)d_in[6];
  const float* Wo  = (const float*)d_in[7];
  const float* bop = (const float*)d_in[8];
  const float* Rf  = (const float*)d_in[9];
  const float* Ri  = (const float*)d_in[10];
  const float* Rg  = (const float*)d_in[11];
  const float* Ro  = (const float*)d_in[12];
  float* dout = (float*)d_out;
  char* ws = (char*)d_ws;

  const size_t o_Wx  = 0;
  const size_t o_Rs  = o_Wx + 2097152;
  const size_t o_bp  = o_Rs + 2097152;
  const size_t o_xsw = o_bp + 8192;
  const size_t o_zx  = o_xsw + 33554432;

  int CH = 64;
  while (CH > 4) {
    const size_t need = o_zx + (size_t)CH * 524288 + (size_t)(CH + 1) * 65536
                      + 524288 + 1024;
    if (need <= ws_size) break;
    CH >>= 1;
  }
  const size_t o_hb = o_zx + (size_t)CH * 524288;
  const size_t o_cs = o_hb + (size_t)(CH + 1) * 65536;
  const size_t o_fl = o_cs + 524288;

  ushort* Wx  = (ushort*)(ws + o_Wx);
  ushort* Rs  = (ushort*)(ws + o_Rs);
  float*  bp  = (float*)(ws + o_bp);
  ushort* xsw = (ushort*)(ws + o_xsw);
  float*  zx  = (float*)(ws + o_zx);
  ushort* hb  = (ushort*)(ws + o_hb);
  float*  csv = (float*)(ws + o_cs);
  int*    fl  = (int*)(ws + o_fl);

  pack_weights<<<256, 256, 0, stream>>>(Wf, Wi, Wg, Wo, Rf, Ri, Rg, Ro,
                                        bfp, bip, bgp, bop, Wx, Rs, bp);
  swizzle_x<<<512, 256, 0, stream>>>(x, xsw);
  hipMemsetAsync(hb, 0, 65536, stream);   // h(0) = 0 (slot 0, all groups)
  hipMemsetAsync(fl, 0, 1024, stream);    // group counters (monotone per launch)

  const int nch = 512 / CH;
  for (int c = 0; c < nch; ++c) {
    const int G = (CH < 16) ? CH : 16;
    zx_gemm<<<dim3(16, G), 512, 0, stream>>>(xsw, Wx, zx, c * CH, CH / G);
    rec_kernel<<<16, 512, 0, stream>>>(Rs, bp, zx, hb, csv, fl, dout, c * CH, CH);
  }
}